// Round 1
// baseline (136.934 us; speedup 1.0000x reference)
//
#include <hip/hip_runtime.h>
#include <hip/hip_bf16.h>

typedef __bf16 bf16x8 __attribute__((ext_vector_type(8)));
typedef __bf16 bf16x4 __attribute__((ext_vector_type(4)));
typedef float f32x4 __attribute__((ext_vector_type(4)));

#define S_LEN 2048
#define D_DIM 64

// Flash-attention forward, causal, bf16 MFMA compute, fp32 I/O.
// Block = 256 threads (4 waves); each wave owns 16 q-rows of a 64-row q-tile.
// K tile staged to LDS [k][d]; V tile staged TRANSPOSED [d][k]; both XOR-swizzled.
__global__ __launch_bounds__(256) void attn_fwd_kernel(
    const float* __restrict__ Vg, const float* __restrict__ Qg,
    const float* __restrict__ Kg, float* __restrict__ Og) {
  __shared__ __align__(16) unsigned char k_lds[64 * 128];    // 8 KB bf16 [k][d]
  __shared__ __align__(16) unsigned char vt_lds[64 * 128];   // 8 KB bf16 [d][k]
  __shared__ __align__(16) unsigned char p_lds[4][16 * 128]; // per-wave 2 KB [q][k]

  const int tid  = threadIdx.x;
  const int lane = tid & 63;
  const int w    = tid >> 6;   // wave 0..3
  const int lr   = lane & 15;
  const int lg   = lane >> 4;  // 0..3

  const int qt   = blockIdx.x;      // q-tile 0..31
  const int bh   = blockIdx.y;      // 0..31
  const int base = bh * (S_LEN * D_DIM);
  const int q0   = qt * 64;

  // ---- Q fragments (held in registers for the whole kernel) ----
  // A-frag for 16x16x32: lane holds row (lane&15), k-cols 8*(lane>>4)+i (+32 per chunk)
  bf16x8 qf[2];
  {
    const float* qp = Qg + base + (q0 + w * 16 + lr) * D_DIM + lg * 8;
    #pragma unroll
    for (int c = 0; c < 2; ++c) {
      float4 f0 = *reinterpret_cast<const float4*>(qp + c * 32);
      float4 f1 = *reinterpret_cast<const float4*>(qp + c * 32 + 4);
      bf16x8 t;
      t[0]=(__bf16)f0.x; t[1]=(__bf16)f0.y; t[2]=(__bf16)f0.z; t[3]=(__bf16)f0.w;
      t[4]=(__bf16)f1.x; t[5]=(__bf16)f1.y; t[6]=(__bf16)f1.z; t[7]=(__bf16)f1.w;
      qf[c] = t;
    }
  }

  f32x4 po[4];                  // O accumulator: 4 d-tiles x 4 rows
  float m_i[4], l_i[4];
  #pragma unroll
  for (int j = 0; j < 4; ++j) {
    po[j] = (f32x4){0.f, 0.f, 0.f, 0.f};
    m_i[j] = -1e30f;
    l_i[j] = 0.f;
  }

  for (int kt = 0; kt <= qt; ++kt) {
    __syncthreads();  // protect LDS from previous iteration's readers

    // ---- stage K tile: fp32 [64][64] -> bf16 k_lds[k][d], swizzled ----
    {
      const float* kg = Kg + base + kt * (64 * D_DIM);
      #pragma unroll
      for (int i = 0; i < 4; ++i) {
        int idx = tid + 256 * i;   // 0..1023
        int r   = idx >> 4;        // row 0..63
        int f4  = idx & 15;        // float4 index
        float4 f = *reinterpret_cast<const float4*>(kg + r * 64 + f4 * 4);
        bf16x4 t;
        t[0]=(__bf16)f.x; t[1]=(__bf16)f.y; t[2]=(__bf16)f.z; t[3]=(__bf16)f.w;
        int b = r * 128 + f4 * 8;
        b ^= (r & 7) << 4;
        *reinterpret_cast<bf16x4*>(&k_lds[b]) = t;
      }
      // ---- stage V transposed: vt_lds[d][k], swizzled ----
      const float* vg = Vg + base + kt * (64 * D_DIM);
      #pragma unroll
      for (int s = 0; s < 2; ++s) {
        int task = tid + 256 * s;  // 0..511
        int d  = task & 63;
        int kb = task >> 6;        // 0..7
        bf16x8 t;
        #pragma unroll
        for (int j = 0; j < 8; ++j)
          t[j] = (__bf16)vg[(kb * 8 + j) * 64 + d];
        int b = d * 128 + kb * 16;
        b ^= (d & 7) << 4;
        *reinterpret_cast<bf16x8*>(&vt_lds[b]) = t;
      }
    }
    __syncthreads();

    // ---- S = (Q K^T) * scale ----
    f32x4 s_acc[4];
    #pragma unroll
    for (int ct = 0; ct < 4; ++ct) s_acc[ct] = (f32x4){0.f, 0.f, 0.f, 0.f};
    #pragma unroll
    for (int ct = 0; ct < 4; ++ct) {
      #pragma unroll
      for (int c = 0; c < 2; ++c) {
        int r = ct * 16 + lr;                      // K row (B-frag col)
        int b = r * 128 + c * 64 + lg * 16;        // + k-dim offset
        b ^= (r & 7) << 4;
        bf16x8 kf = *reinterpret_cast<const bf16x8*>(&k_lds[b]);
        s_acc[ct] = __builtin_amdgcn_mfma_f32_16x16x32_bf16(qf[c], kf, s_acc[ct], 0, 0, 0);
      }
    }

    // ---- scale + causal mask + online softmax ----
    const float scale = 0.125f;  // 1/sqrt(64)
    const bool diag = (kt == qt);
    float tmax[4] = {-1e30f, -1e30f, -1e30f, -1e30f};
    #pragma unroll
    for (int ct = 0; ct < 4; ++ct) {
      #pragma unroll
      for (int j = 0; j < 4; ++j) {
        float s = s_acc[ct][j] * scale;
        if (diag && (qt * 64 + ct * 16 + lr) > (q0 + w * 16 + lg * 4 + j)) s = -1e30f;
        s_acc[ct][j] = s;
        tmax[j] = fmaxf(tmax[j], s);
      }
    }
    #pragma unroll
    for (int off = 1; off < 16; off <<= 1) {
      #pragma unroll
      for (int j = 0; j < 4; ++j)
        tmax[j] = fmaxf(tmax[j], __shfl_xor(tmax[j], off));
    }

    float alpha[4], psum[4] = {0.f, 0.f, 0.f, 0.f};
    #pragma unroll
    for (int j = 0; j < 4; ++j) {
      float mn = fmaxf(m_i[j], tmax[j]);
      alpha[j] = __expf(m_i[j] - mn);
      m_i[j] = mn;
    }
    #pragma unroll
    for (int ct = 0; ct < 4; ++ct) {
      #pragma unroll
      for (int j = 0; j < 4; ++j) {
        float p = __expf(s_acc[ct][j] - m_i[j]);
        psum[j] += p;
        int row = lg * 4 + j;
        int col = ct * 16 + lr;
        int b = row * 128 + col * 2;
        b ^= (row & 7) << 4;
        *reinterpret_cast<__bf16*>(&p_lds[w][b]) = (__bf16)p;
      }
    }
    #pragma unroll
    for (int off = 1; off < 16; off <<= 1) {
      #pragma unroll
      for (int j = 0; j < 4; ++j)
        psum[j] += __shfl_xor(psum[j], off);
    }
    #pragma unroll
    for (int j = 0; j < 4; ++j) {
      l_i[j] = l_i[j] * alpha[j] + psum[j];
      #pragma unroll
      for (int dt = 0; dt < 4; ++dt) po[dt][j] *= alpha[j];
    }

    // ---- O += P V  (A-frag from p_lds, B-frag from vt_lds) ----
    #pragma unroll
    for (int dt = 0; dt < 4; ++dt) {
      #pragma unroll
      for (int c = 0; c < 2; ++c) {
        int ab = lr * 128 + c * 64 + lg * 16;
        ab ^= (lr & 7) << 4;
        bf16x8 pa = *reinterpret_cast<const bf16x8*>(&p_lds[w][ab]);
        int vrow = dt * 16 + lr;
        int bb = vrow * 128 + c * 64 + lg * 16;
        bb ^= (vrow & 7) << 4;
        bf16x8 vb = *reinterpret_cast<const bf16x8*>(&vt_lds[bb]);
        po[dt] = __builtin_amdgcn_mfma_f32_16x16x32_bf16(pa, vb, po[dt], 0, 0, 0);
      }
    }
  }

  // ---- epilogue: normalize and store fp32 ----
  #pragma unroll
  for (int j = 0; j < 4; ++j) {
    float inv = 1.0f / l_i[j];
    int row = q0 + w * 16 + lg * 4 + j;
    #pragma unroll
    for (int dt = 0; dt < 4; ++dt) {
      Og[base + row * D_DIM + dt * 16 + lr] = po[dt][j] * inv;
    }
  }
}

extern "C" void kernel_launch(void* const* d_in, const int* in_sizes, int n_in,
                              void* d_out, int out_size, void* d_ws, size_t ws_size,
                              hipStream_t stream) {
  const float* V = (const float*)d_in[0];
  const float* Q = (const float*)d_in[1];
  const float* K = (const float*)d_in[2];
  float* O = (float*)d_out;
  int bh = in_sizes[0] / (S_LEN * D_DIM);  // B*H = 32
  dim3 grid(S_LEN / 64, bh);
  attn_fwd_kernel<<<grid, 256, 0, stream>>>(V, Q, K, O);
}

// Round 2
// 108.145 us; speedup vs baseline: 1.2662x; 1.2662x over previous
//
#include <hip/hip_runtime.h>
#include <hip/hip_bf16.h>

typedef __bf16 bf16x8 __attribute__((ext_vector_type(8)));
typedef __bf16 bf16x4 __attribute__((ext_vector_type(4)));
typedef float f32x4 __attribute__((ext_vector_type(4)));

#define S_LEN 2048
#define D_DIM 64
#define NQT   (S_LEN / 64)   // 32 q-tiles of 64 rows

// Flash-attention fwd, causal, bf16 MFMA, fp32 I/O.
// Block = 256 threads (4 waves). Block pi handles q-tiles pi and 31-pi
// (balanced: always 33 compute-iterations). K/V staged via register
// prefetch into double-buffered LDS; one barrier per k-tile.
__global__ __launch_bounds__(256) void attn_fwd_kernel(
    const float* __restrict__ Vg, const float* __restrict__ Qg,
    const float* __restrict__ Kg, float* __restrict__ Og) {
  __shared__ __align__(16) unsigned char k_lds[2][64 * 128];   // 16 KB  [k][d] bf16
  __shared__ __align__(16) unsigned char vt_lds[2][64 * 128];  // 16 KB  [d][k] bf16
  __shared__ __align__(16) unsigned char p_lds[4][16 * 128];   // 8 KB   per-wave [q][k]

  const int tid  = threadIdx.x;
  const int lane = tid & 63;
  const int w    = tid >> 6;   // wave 0..3
  const int lr   = lane & 15;
  const int lg   = lane >> 4;  // 0..3
  const int d_   = tid & 63;   // V-stage: d column
  const int kb   = tid >> 6;   // V-stage: k-block 0..3 (and +4)

  const int pi    = blockIdx.x;           // 0..15
  const int qt_lo = pi;
  const int qt_hi = NQT - 1 - pi;
  const int bh    = blockIdx.y;
  const long base = (long)bh * (S_LEN * D_DIM);
  const int q0_lo = qt_lo * 64;
  const int q0_hi = qt_hi * 64;

  // ---- Q fragments, pre-scaled by 1/8 (exact pow2, no precision change) ----
  bf16x8 qf_lo[2], qf_hi[2];
  {
    const float* qpl = Qg + base + (q0_lo + w * 16 + lr) * D_DIM + lg * 8;
    const float* qph = Qg + base + (q0_hi + w * 16 + lr) * D_DIM + lg * 8;
    #pragma unroll
    for (int c = 0; c < 2; ++c) {
      float4 f0 = *reinterpret_cast<const float4*>(qpl + c * 32);
      float4 f1 = *reinterpret_cast<const float4*>(qpl + c * 32 + 4);
      bf16x8 t;
      t[0]=(__bf16)(f0.x*0.125f); t[1]=(__bf16)(f0.y*0.125f);
      t[2]=(__bf16)(f0.z*0.125f); t[3]=(__bf16)(f0.w*0.125f);
      t[4]=(__bf16)(f1.x*0.125f); t[5]=(__bf16)(f1.y*0.125f);
      t[6]=(__bf16)(f1.z*0.125f); t[7]=(__bf16)(f1.w*0.125f);
      qf_lo[c] = t;
      f0 = *reinterpret_cast<const float4*>(qph + c * 32);
      f1 = *reinterpret_cast<const float4*>(qph + c * 32 + 4);
      t[0]=(__bf16)(f0.x*0.125f); t[1]=(__bf16)(f0.y*0.125f);
      t[2]=(__bf16)(f0.z*0.125f); t[3]=(__bf16)(f0.w*0.125f);
      t[4]=(__bf16)(f1.x*0.125f); t[5]=(__bf16)(f1.y*0.125f);
      t[6]=(__bf16)(f1.z*0.125f); t[7]=(__bf16)(f1.w*0.125f);
      qf_hi[c] = t;
    }
  }

  // ones B-frag: B[k][n] = (n==0) -> row-sum lands in col 0 of the accumulator
  bf16x8 onesf;
  #pragma unroll
  for (int j = 0; j < 8; ++j) onesf[j] = (lr == 0) ? (__bf16)1.0f : (__bf16)0.0f;

  f32x4 po_lo[4], po_hi[4], pl_lo, pl_hi;
  float m_lo[4], m_hi[4];
  #pragma unroll
  for (int j = 0; j < 4; ++j) {
    po_lo[j] = (f32x4){0.f,0.f,0.f,0.f};
    po_hi[j] = (f32x4){0.f,0.f,0.f,0.f};
    m_lo[j] = -1e30f; m_hi[j] = -1e30f;
  }
  pl_lo = (f32x4){0.f,0.f,0.f,0.f};
  pl_hi = (f32x4){0.f,0.f,0.f,0.f};

  // ---- staging: global -> regs (prefetch), regs -> LDS (bf16, swizzled) ----
  float4 kreg[4];
  float  vreg[16];

  auto load_regs = [&](int kt) {
    const float* kg = Kg + base + kt * (64 * D_DIM);
    #pragma unroll
    for (int i = 0; i < 4; ++i) {
      int idx = tid + 256 * i;
      int r = idx >> 4, f4 = idx & 15;
      kreg[i] = *reinterpret_cast<const float4*>(kg + r * 64 + f4 * 4);
    }
    const float* vg = Vg + base + kt * (64 * D_DIM);
    #pragma unroll
    for (int j = 0; j < 8; ++j) {
      vreg[j]     = vg[(kb * 8 + j) * 64 + d_];
      vreg[8 + j] = vg[((kb + 4) * 8 + j) * 64 + d_];
    }
  };

  auto write_buf = [&](int sel) {
    unsigned char* kl = k_lds[sel];
    unsigned char* vl = vt_lds[sel];
    #pragma unroll
    for (int i = 0; i < 4; ++i) {
      int idx = tid + 256 * i;
      int r = idx >> 4, f4 = idx & 15;
      bf16x4 t;
      t[0]=(__bf16)kreg[i].x; t[1]=(__bf16)kreg[i].y;
      t[2]=(__bf16)kreg[i].z; t[3]=(__bf16)kreg[i].w;
      int b = r * 128 + f4 * 8;
      b ^= (r & 7) << 4;
      *reinterpret_cast<bf16x4*>(&kl[b]) = t;
    }
    bf16x8 t0, t1;
    #pragma unroll
    for (int j = 0; j < 8; ++j) { t0[j] = (__bf16)vreg[j]; t1[j] = (__bf16)vreg[8+j]; }
    int b0 = d_ * 128 + kb * 16;        b0 ^= (d_ & 7) << 4;
    int b1 = d_ * 128 + (kb + 4) * 16;  b1 ^= (d_ & 7) << 4;
    *reinterpret_cast<bf16x8*>(&vl[b0]) = t0;
    *reinterpret_cast<bf16x8*>(&vl[b1]) = t1;
  };

  auto compute = [&](const bf16x8* qf, f32x4* po, f32x4& pl, float* m_i,
                     int q0, int kt, bool diag, int sel) {
    const unsigned char* kl = k_lds[sel];
    const unsigned char* vl = vt_lds[sel];
    // S = Q K^T (scale pre-folded into Q)
    f32x4 s_acc[4];
    #pragma unroll
    for (int ct = 0; ct < 4; ++ct) s_acc[ct] = (f32x4){0.f,0.f,0.f,0.f};
    #pragma unroll
    for (int ct = 0; ct < 4; ++ct) {
      #pragma unroll
      for (int c = 0; c < 2; ++c) {
        int r = ct * 16 + lr;
        int b = r * 128 + c * 64 + lg * 16;
        b ^= (r & 7) << 4;
        bf16x8 kf = *reinterpret_cast<const bf16x8*>(&kl[b]);
        s_acc[ct] = __builtin_amdgcn_mfma_f32_16x16x32_bf16(qf[c], kf, s_acc[ct], 0, 0, 0);
      }
    }
    // mask + row max
    float tmax[4] = {-1e30f,-1e30f,-1e30f,-1e30f};
    #pragma unroll
    for (int ct = 0; ct < 4; ++ct) {
      #pragma unroll
      for (int j = 0; j < 4; ++j) {
        float s = s_acc[ct][j];
        if (diag && (kt * 64 + ct * 16 + lr) > (q0 + w * 16 + lg * 4 + j)) s = -1e30f;
        s_acc[ct][j] = s;
        tmax[j] = fmaxf(tmax[j], s);
      }
    }
    #pragma unroll
    for (int off = 1; off < 16; off <<= 1) {
      #pragma unroll
      for (int j = 0; j < 4; ++j)
        tmax[j] = fmaxf(tmax[j], __shfl_xor(tmax[j], off));
    }
    float alpha[4];
    #pragma unroll
    for (int j = 0; j < 4; ++j) {
      float mn = fmaxf(m_i[j], tmax[j]);
      alpha[j] = __expf(m_i[j] - mn);
      m_i[j] = mn;
    }
    // P = exp(S - m) -> per-wave LDS (bf16, swizzled)
    #pragma unroll
    for (int ct = 0; ct < 4; ++ct) {
      #pragma unroll
      for (int j = 0; j < 4; ++j) {
        float p = __expf(s_acc[ct][j] - m_i[j]);
        int row = lg * 4 + j;
        int col = ct * 16 + lr;
        int b = row * 128 + col * 2;
        b ^= (row & 7) << 4;
        *reinterpret_cast<__bf16*>(&p_lds[w][b]) = (__bf16)p;
      }
    }
    // rescale accumulators
    #pragma unroll
    for (int j = 0; j < 4; ++j) {
      pl[j] *= alpha[j];
      #pragma unroll
      for (int dt = 0; dt < 4; ++dt) po[dt][j] *= alpha[j];
    }
    // O += P V ; l += P * ones
    #pragma unroll
    for (int c = 0; c < 2; ++c) {
      int ab = lr * 128 + c * 64 + lg * 16;
      ab ^= (lr & 7) << 4;
      bf16x8 pa = *reinterpret_cast<const bf16x8*>(&p_lds[w][ab]);
      pl = __builtin_amdgcn_mfma_f32_16x16x32_bf16(pa, onesf, pl, 0, 0, 0);
      #pragma unroll
      for (int dt = 0; dt < 4; ++dt) {
        int vrow = dt * 16 + lr;
        int bb = vrow * 128 + c * 64 + lg * 16;
        bb ^= (vrow & 7) << 4;
        bf16x8 vb = *reinterpret_cast<const bf16x8*>(&vl[bb]);
        po[dt] = __builtin_amdgcn_mfma_f32_16x16x32_bf16(pa, vb, po[dt], 0, 0, 0);
      }
    }
  };

  // ---- main loop: one barrier per k-tile ----
  load_regs(0);
  write_buf(0);
  __syncthreads();

  for (int kt = 0; kt <= qt_hi; ++kt) {
    int sel = kt & 1;
    if (kt < qt_hi) load_regs(kt + 1);
    compute(qf_hi, po_hi, pl_hi, m_hi, q0_hi, kt, kt == qt_hi, sel);
    if (kt <= qt_lo) compute(qf_lo, po_lo, pl_lo, m_lo, q0_lo, kt, kt == qt_lo, sel);
    if (kt < qt_hi) write_buf(sel ^ 1);
    __syncthreads();
  }

  // ---- epilogue ----
  #pragma unroll
  for (int j = 0; j < 4; ++j) {
    float lv  = __shfl(pl_hi[j], lane & 48);
    float inv = 1.0f / lv;
    int row = q0_hi + w * 16 + lg * 4 + j;
    #pragma unroll
    for (int dt = 0; dt < 4; ++dt)
      Og[base + row * D_DIM + dt * 16 + lr] = po_hi[dt][j] * inv;
  }
  #pragma unroll
  for (int j = 0; j < 4; ++j) {
    float lv  = __shfl(pl_lo[j], lane & 48);
    float inv = 1.0f / lv;
    int row = q0_lo + w * 16 + lg * 4 + j;
    #pragma unroll
    for (int dt = 0; dt < 4; ++dt)
      Og[base + row * D_DIM + dt * 16 + lr] = po_lo[dt][j] * inv;
  }
}

extern "C" void kernel_launch(void* const* d_in, const int* in_sizes, int n_in,
                              void* d_out, int out_size, void* d_ws, size_t ws_size,
                              hipStream_t stream) {
  const float* V = (const float*)d_in[0];
  const float* Q = (const float*)d_in[1];
  const float* K = (const float*)d_in[2];
  float* O = (float*)d_out;
  int bh = in_sizes[0] / (S_LEN * D_DIM);  // B*H = 32
  dim3 grid(NQT / 2, bh);
  attn_fwd_kernel<<<grid, 256, 0, stream>>>(V, Q, K, O);
}